// Round 15
// baseline (511.562 us; speedup 1.0000x reference)
//
#include <hip/hip_runtime.h>
#include <hip/hip_fp16.h>

#define N_NODES 100000
#define N_EDGES 1600000
#define D 128
#define SCAN_NB ((N_NODES + 1023) / 1024)   // 98
#define CHK 128                             // edge chunks
#define CHUNK_E (N_EDGES / CHK)             // 12500 edges/chunk
#define HR 8                                // hist node ranges
#define HRN (N_NODES / HR)                  // 12500 nodes/range
#define HRU (HRN / 4)                       // 3125 uints (12.5 KB LDS)
#define PP_STRIDE (N_NODES / 4)             // 25000 uints per chunk (dst only)
#define NSH4 4                              // scatter shards (R8-proven config)
#define SH4 (N_NODES / NSH4)                // 25000 nodes/shard
#define SH4_U (SH4 / 4)                     // 6250 uints (25 KB LDS)
#define WR 40                               // wacc: node ranges
#define WRN (N_NODES / WR)                  // 2500 nodes/range (10 KB float LDS)
#define WRU (WRN / 4)                       // 625 packed count uints (2.5 KB)
#define WG 64                               // wacc: edge groups (2560 blocks)
#define WGE (N_EDGES / WG)                  // 25000 edges/group

typedef _Float16 f16x4 __attribute__((ext_vector_type(4)));
typedef _Float16 f16x8 __attribute__((ext_vector_type(8)));
typedef float f32x4 __attribute__((ext_vector_type(4)));
typedef float f32x2 __attribute__((ext_vector_type(2)));

// ---------------------------------------------------------------------------
// Pass A: dst-only LDS histogram, 8-bit packed, eighth node-ranges.
// block = (range r, chunk c); 1024 blocks; 12.5 KB LDS.
__global__ __launch_bounds__(256) void
k_hist(const int* __restrict__ dst, unsigned int* __restrict__ pp) {
    __shared__ unsigned int h[HRU];  // 12.5 KB
    int r = blockIdx.x >> 7, c = blockIdx.x & (CHK - 1);
    int lo = r * HRN;
    for (int i = threadIdx.x; i < HRU; i += 256) h[i] = 0;
    __syncthreads();
    int e0 = c * CHUNK_E;
    for (int i = e0 + threadIdx.x; i < e0 + CHUNK_E; i += 256) {
        int v = dst[i] - lo;
        if ((unsigned)v < HRN)
            atomicAdd(&h[v >> 2], 1u << ((v & 3) * 8));
    }
    __syncthreads();
    unsigned int* po = pp + (size_t)c * PP_STRIDE + r * HRU;
    for (int i = threadIdx.x; i < HRU; i += 256) po[i] = h[i];
}

// Pass B: dst totals -> cnt_dst; partials -> exclusive per-chunk prefix
// (8-bit packed) in place.
__global__ void k_merge(unsigned int* __restrict__ pp, int* __restrict__ cnt_dst) {
    int u = blockIdx.x * blockDim.x + threadIdx.x;
    if (u >= PP_STRIDE) return;
    unsigned int* p = pp + u;
    int s0 = 0, s1 = 0, s2 = 0, s3 = 0;
#pragma unroll 8
    for (int c = 0; c < CHK; c++) {
        unsigned int v = p[(size_t)c * PP_STRIDE];
        p[(size_t)c * PP_STRIDE] =
            (unsigned)s0 | ((unsigned)s1 << 8) | ((unsigned)s2 << 16) | ((unsigned)s3 << 24);
        s0 += v & 255; s1 += (v >> 8) & 255; s2 += (v >> 16) & 255; s3 += (v >> 24) & 255;
    }
    cnt_dst[4 * u + 0] = s0; cnt_dst[4 * u + 1] = s1;
    cnt_dst[4 * u + 2] = s2; cnt_dst[4 * u + 3] = s3;
}

// scan cnt_dst -> rpD (inclusive per block) + block sums
__global__ __launch_bounds__(1024) void
k_scan1(const int* __restrict__ cnt, int* __restrict__ rp1, int* __restrict__ bs) {
    __shared__ int s[1024];
    int tid = threadIdx.x;
    int i = blockIdx.x * 1024 + tid;
    int v = (i < N_NODES) ? cnt[i] : 0;
    s[tid] = v;
    __syncthreads();
    for (int d = 1; d < 1024; d <<= 1) {
        int t = (tid >= d) ? s[tid - d] : 0;
        __syncthreads();
        s[tid] += t;
        __syncthreads();
    }
    if (i < N_NODES) rp1[i] = s[tid];
    if (tid == 1023) bs[blockIdx.x] = s[1023];
}

__global__ void k_scan2(int* __restrict__ bs) {
    __shared__ int s[128];
    int tid = threadIdx.x;
    int v = (tid < SCAN_NB) ? bs[tid] : 0;
    s[tid] = v;
    __syncthreads();
    for (int d = 1; d < 128; d <<= 1) {
        int t = (tid >= d) ? s[tid - d] : 0;
        __syncthreads();
        s[tid] += t;
        __syncthreads();
    }
    if (tid < SCAN_NB) bs[tid] = s[tid] - v;  // exclusive
}

// finalize rpD + nd + zero colsum (ns comes from k_wmerge)
__global__ void k_scan3nd(int* __restrict__ rpD, const int* __restrict__ bsD,
                          const int* __restrict__ cnt_dst,
                          float* __restrict__ nd, float* __restrict__ colsum) {
    int i = blockIdx.x * blockDim.x + threadIdx.x;
    if (i >= N_NODES) return;
    rpD[1 + i] += bsD[i >> 10];
    if (i == 0) rpD[0] = 0;
    if (i < 128) colsum[i] = 0.0f;
    nd[i] = rsqrtf((float)max(cnt_dst[i], 1));
}

// Pass C: counting-sort by dst, payload src. R8-proven config: separate kernel,
// 4 shards (blockIdx&3), 512 blocks, 25 KB LDS 8-bit rank counters.
__global__ __launch_bounds__(256) void
k_scatter_dst(const int* __restrict__ src, const int* __restrict__ dst,
              const int* __restrict__ rpD, const unsigned int* __restrict__ pp,
              int* __restrict__ csr_src) {
    __shared__ unsigned int cur[SH4_U];  // 25 KB
    int sh = blockIdx.x & 3, c = blockIdx.x >> 2;
    int lo = sh * SH4;
    const unsigned int* pre = pp + (size_t)c * PP_STRIDE;
    for (int i = threadIdx.x; i < SH4_U; i += 256) cur[i] = 0;
    __syncthreads();
    int e0 = c * CHUNK_E;
    for (int i = e0 + threadIdx.x; i < e0 + CHUNK_E; i += 256) {
        int dfull = dst[i];
        int d = dfull - lo;
        if ((unsigned)d < SH4) {
            int sft = (d & 3) * 8;
            int rank = (atomicAdd(&cur[d >> 2], 1u << sft) >> sft) & 255;
            int p8 = (pre[dfull >> 2] >> ((dfull & 3) * 8)) & 255;
            csr_src[rpD[dfull] + p8 + rank] = src[i];
        }
    }
}

// wacc: per-src accumulation of nd[dst] AND out-degree count (absorbs the src
// histogram — a sum needs no sort). LDS float bins + packed 8-bit counts;
// no global atomics. block = (range r, group g); 2560 blocks, 12.5 KB LDS
// (R13 512 blocks -> 21% occ -> 140us; R14 1024 -> 40% -> 78us; scaling says
// more blocks is still the lever).
__global__ __launch_bounds__(256) void
k_wacc(const int* __restrict__ src, const int* __restrict__ dst,
       const float* __restrict__ nd, float* __restrict__ wpart,
       unsigned int* __restrict__ cpart) {
    __shared__ float acc[WRN];        // 10 KB
    __shared__ unsigned int cnt[WRU]; // 2.5 KB
    int r = blockIdx.x % WR, g = blockIdx.x / WR;
    int lo = r * WRN;
    for (int i = threadIdx.x; i < WRN; i += 256) acc[i] = 0.0f;
    for (int i = threadIdx.x; i < WRU; i += 256) cnt[i] = 0;
    __syncthreads();
    int e0 = g * WGE;
    for (int i = e0 + threadIdx.x; i < e0 + WGE; i += 256) {
        int s = src[i] - lo;
        if ((unsigned)s < WRN) {
            atomicAdd(&acc[s], nd[dst[i]]);
            atomicAdd(&cnt[s >> 2], 1u << ((s & 3) * 8));
        }
    }
    __syncthreads();
    float* po = wpart + (size_t)g * N_NODES + lo;
    for (int i = threadIdx.x; i < WRN; i += 256) po[i] = acc[i];
    unsigned int* co = cpart + (size_t)g * (N_NODES / 4) + (lo >> 2);
    for (int i = threadIdx.x; i < WRU; i += 256) co[i] = cnt[i];
}

// wmerge: ns[n] = rsqrt(max(deg_out,1)); wsum[n] = ns[n] * sum_g wpart[g][n]
__global__ void k_wmerge(const float* __restrict__ wpart,
                         const unsigned int* __restrict__ cpart,
                         float* __restrict__ ns, float* __restrict__ wsum) {
    int n = blockIdx.x * blockDim.x + threadIdx.x;
    if (n >= N_NODES) return;
    float s = 0.0f;
    int c = 0;
    int sft = (n & 3) * 8;
#pragma unroll 8
    for (int g = 0; g < WG; g++) {
        s += wpart[(size_t)g * N_NODES + n];
        c += (cpart[(size_t)g * (N_NODES / 4) + (n >> 2)] >> sft) & 255;
    }
    float nsv = rsqrtf((float)max(c, 1));
    ns[n] = nsv;
    wsum[n] = s * nsv;
}

// fused prep: blocks [0,128): Wt16[l][n][k] = half(Wl[k][n]);
//             blocks [128,...): x8[n][:] = fp8(h[n][:] * ns[n])
__global__ void k_prep(const float* __restrict__ W0, const float* __restrict__ W1,
                       __half* __restrict__ Wt, const float* __restrict__ x,
                       const float* __restrict__ ns, unsigned int* __restrict__ out) {
    if (blockIdx.x < 128) {
        int i = blockIdx.x * 256 + threadIdx.x;  // over 2*D*D
        int l = i >> 14, r = i & (D * D - 1);
        int n = r >> 7, k = r & 127;
        const float* W = l ? W1 : W0;
        Wt[i] = __float2half(W[k * D + n]);
        return;
    }
    int i = (blockIdx.x - 128) * 256 + threadIdx.x;  // over N*D/4
    if (i >= N_NODES * (D / 4)) return;
    int n = i >> 5;
    float4 v = ((const float4*)x)[i];
    float s = ns[n];
    int u = __builtin_amdgcn_cvt_pk_fp8_f32(v.x * s, v.y * s, 0, false);
    u = __builtin_amdgcn_cvt_pk_fp8_f32(v.z * s, v.w * s, u, true);
    out[i] = (unsigned int)u;
}

// pull SpMM (fp8 gather -> fp32 accum -> fp16 agg): one wave per node,
// 2 edges per gather instruction (lane reads uint = 4 fp8; 32 lanes/row).
__global__ __launch_bounds__(256) void
k_spmm(const unsigned char* __restrict__ x8, const int* __restrict__ row_ptr,
       const int* __restrict__ csr_src, __half* __restrict__ agg) {
    int wave = (blockIdx.x * blockDim.x + threadIdx.x) >> 6;
    int lane = threadIdx.x & 63;
    int hf = lane >> 5, l32 = lane & 31;
    if (wave >= N_NODES) return;
    int beg = row_ptr[wave], end = row_ptr[wave + 1];
    float a0 = 0.f, a1 = 0.f, a2 = 0.f, a3 = 0.f;
    int j = beg;
    for (; j + 7 < end; j += 8) {
#pragma unroll
        for (int p = 0; p < 4; p++) {
            int s0 = csr_src[j + 2 * p];
            int s1 = csr_src[j + 2 * p + 1];
            int s = hf ? s1 : s0;
            unsigned int u = *(const unsigned int*)(x8 + (size_t)s * D + 4 * l32);
            f32x2 lo = __builtin_amdgcn_cvt_pk_f32_fp8(u, false);
            f32x2 hi = __builtin_amdgcn_cvt_pk_f32_fp8(u, true);
            a0 += lo[0]; a1 += lo[1]; a2 += hi[0]; a3 += hi[1];
        }
    }
    for (; j + 1 < end; j += 2) {
        int s0 = csr_src[j], s1 = csr_src[j + 1];
        int s = hf ? s1 : s0;
        unsigned int u = *(const unsigned int*)(x8 + (size_t)s * D + 4 * l32);
        f32x2 lo = __builtin_amdgcn_cvt_pk_f32_fp8(u, false);
        f32x2 hi = __builtin_amdgcn_cvt_pk_f32_fp8(u, true);
        a0 += lo[0]; a1 += lo[1]; a2 += hi[0]; a3 += hi[1];
    }
    if (j < end && hf == 0) {
        int s = csr_src[j];
        unsigned int u = *(const unsigned int*)(x8 + (size_t)s * D + 4 * l32);
        f32x2 lo = __builtin_amdgcn_cvt_pk_f32_fp8(u, false);
        f32x2 hi = __builtin_amdgcn_cvt_pk_f32_fp8(u, true);
        a0 += lo[0]; a1 += lo[1]; a2 += hi[0]; a3 += hi[1];
    }
    a0 += __shfl_xor(a0, 32, 64);
    a1 += __shfl_xor(a1, 32, 64);
    a2 += __shfl_xor(a2, 32, 64);
    a3 += __shfl_xor(a3, 32, 64);
    if (hf == 0) {
        f16x4 o;
        o[0] = (_Float16)a0; o[1] = (_Float16)a1; o[2] = (_Float16)a2; o[3] = (_Float16)a3;
        ((f16x4*)(agg + (size_t)wave * D))[l32] = o;
    }
}

// MFMA GEMM (layer 0): A fp16 (agg), out fp8 rows (pre-scaled by ns).
__global__ __launch_bounds__(256) void
k_gemm_mfma(const __half* __restrict__ A, const __half* __restrict__ Wt,
            const float* __restrict__ b, const float* __restrict__ nd,
            const float* __restrict__ ns, unsigned char* __restrict__ out) {
    int w = threadIdx.x >> 6, lane = threadIdx.x & 63;
    int m = lane & 15, q = lane >> 4;
    int row0 = blockIdx.x * 128 + w * 32;

    f16x8 zf;
#pragma unroll
    for (int j = 0; j < 8; j++) zf[j] = (_Float16)0;
    f16x8 af[2][4];
#pragma unroll
    for (int g = 0; g < 2; g++) {
        int arow = row0 + g * 16 + m;
        const f16x8* pa = (const f16x8*)(A + (size_t)arow * D);
        bool aok = arow < N_NODES;
#pragma unroll
        for (int ks = 0; ks < 4; ks++) af[g][ks] = aok ? pa[ks * 4 + q] : zf;
    }

    const f16x8* pb = (const f16x8*)Wt;
    f32x4 acc[2][8];
#pragma unroll
    for (int g = 0; g < 2; g++)
#pragma unroll
        for (int nt = 0; nt < 8; nt++) acc[g][nt] = (f32x4){0.f, 0.f, 0.f, 0.f};

#pragma unroll
    for (int ks = 0; ks < 4; ks++) {
#pragma unroll
        for (int nt = 0; nt < 8; nt++) {
            f16x8 bf = pb[((nt * 16 + m) << 4) + (ks << 2) + q];
            acc[0][nt] = __builtin_amdgcn_mfma_f32_16x16x32_f16(af[0][ks], bf, acc[0][nt], 0, 0, 0);
            acc[1][nt] = __builtin_amdgcn_mfma_f32_16x16x32_f16(af[1][ks], bf, acc[1][nt], 0, 0, 0);
        }
    }

#pragma unroll
    for (int g = 0; g < 2; g++) {
        int er = row0 + g * 16 + q * 4;
        float sd[4], ss[4];
#pragma unroll
        for (int r = 0; r < 4; r++) {
            int n = er + r;
            bool ok = n < N_NODES;
            sd[r] = ok ? nd[n] : 0.0f;
            ss[r] = ok ? ns[n] : 0.0f;
        }
#pragma unroll
        for (int nt = 0; nt < 8; nt++) {
            int col = nt * 16 + m;
            float bc = b[col];
#pragma unroll
            for (int r = 0; r < 4; r++) {
                int n = er + r;
                if (n < N_NODES) {
                    float v = fmaxf(sd[r] * acc[g][nt][r] + bc, 0.0f) * ss[r];
                    int pk = __builtin_amdgcn_cvt_pk_fp8_f32(v, v, 0, false);
                    out[(size_t)n * D + col] = (unsigned char)(pk & 0xff);
                }
            }
        }
    }
}

// MFMA GEMM (layer 1 + fused final reduction):
// colsum[col] += sum_n wsum[n] * relu(nd[n]*(A@W1)[n][col] + b1[col])
__global__ __launch_bounds__(256) void
k_gemm_red(const __half* __restrict__ A, const __half* __restrict__ Wt,
           const float* __restrict__ b, const float* __restrict__ nd,
           const float* __restrict__ wsum, float* __restrict__ colsum) {
    __shared__ float red[128];
    int tid = threadIdx.x;
    if (tid < 128) red[tid] = 0.0f;
    __syncthreads();

    int w = tid >> 6, lane = tid & 63;
    int m = lane & 15, q = lane >> 4;
    int row0 = blockIdx.x * 128 + w * 32;

    f16x8 zf;
#pragma unroll
    for (int j = 0; j < 8; j++) zf[j] = (_Float16)0;
    f16x8 af[2][4];
#pragma unroll
    for (int g = 0; g < 2; g++) {
        int arow = row0 + g * 16 + m;
        const f16x8* pa = (const f16x8*)(A + (size_t)arow * D);
        bool aok = arow < N_NODES;
#pragma unroll
        for (int ks = 0; ks < 4; ks++) af[g][ks] = aok ? pa[ks * 4 + q] : zf;
    }

    const f16x8* pb = (const f16x8*)Wt;
    f32x4 acc[2][8];
#pragma unroll
    for (int g = 0; g < 2; g++)
#pragma unroll
        for (int nt = 0; nt < 8; nt++) acc[g][nt] = (f32x4){0.f, 0.f, 0.f, 0.f};

#pragma unroll
    for (int ks = 0; ks < 4; ks++) {
#pragma unroll
        for (int nt = 0; nt < 8; nt++) {
            f16x8 bf = pb[((nt * 16 + m) << 4) + (ks << 2) + q];
            acc[0][nt] = __builtin_amdgcn_mfma_f32_16x16x32_f16(af[0][ks], bf, acc[0][nt], 0, 0, 0);
            acc[1][nt] = __builtin_amdgcn_mfma_f32_16x16x32_f16(af[1][ks], bf, acc[1][nt], 0, 0, 0);
        }
    }

    float sd[2][4], sw[2][4];
#pragma unroll
    for (int g = 0; g < 2; g++) {
        int er = row0 + g * 16 + q * 4;
#pragma unroll
        for (int r = 0; r < 4; r++) {
            int n = er + r;
            bool ok = n < N_NODES;
            sd[g][r] = ok ? nd[n] : 0.0f;
            sw[g][r] = ok ? wsum[n] : 0.0f;
        }
    }
#pragma unroll
    for (int nt = 0; nt < 8; nt++) {
        int col = nt * 16 + m;
        float bc = b[col];
        float pc = 0.0f;
#pragma unroll
        for (int g = 0; g < 2; g++)
#pragma unroll
            for (int r = 0; r < 4; r++)
                pc += sw[g][r] * fmaxf(sd[g][r] * acc[g][nt][r] + bc, 0.0f);
        atomicAdd(&red[col], pc);
    }
    __syncthreads();
    if (tid < 128) unsafeAtomicAdd(&colsum[tid], red[tid]);
}

// out[j] = (colsum/N) @ W2 [:,j] + b2[j]
__global__ void k_final(const float* __restrict__ colsum, const float* __restrict__ W,
                        const float* __restrict__ b, float* __restrict__ out) {
    __shared__ float m[128];
    int j = threadIdx.x;
    m[j] = colsum[j] * (1.0f / N_NODES);
    __syncthreads();
    float acc = b[j];
    for (int k = 0; k < 128; k++)
        acc = fmaf(m[k], W[(size_t)k * D + j], acc);
    out[j] = acc;
}

extern "C" void kernel_launch(void* const* d_in, const int* in_sizes, int n_in,
                              void* d_out, int out_size, void* d_ws, size_t ws_size,
                              hipStream_t stream) {
    const float* h   = (const float*)d_in[0];
    const int*   src = (const int*)d_in[1];
    const int*   dst = (const int*)d_in[2];
    const float* W0  = (const float*)d_in[3];
    const float* b0  = (const float*)d_in[4];
    const float* W1  = (const float*)d_in[5];
    const float* b1  = (const float*)d_in[6];
    const float* W2  = (const float*)d_in[7];
    const float* b2  = (const float*)d_in[8];
    float* out = (float*)d_out;

    // workspace (~79 MB); pp (12.8 MB) dead after scatter -> x8 aliases it exactly
    float*         ns      = (float*)d_ws;                       // N
    float*         nd      = ns + N_NODES;                       // N
    float*         wsum    = nd + N_NODES;                       // N
    float*         colsum  = wsum + N_NODES;                     // 128
    int*           rpD     = (int*)(colsum + 128);               // N+1
    int*           cnt_dst = rpD + N_NODES + 1;                  // N
    int*           bsD     = cnt_dst + N_NODES;                  // 128
    __half*        Wt16    = (__half*)(bsD + 128);               // 2*D*D
    int*           csr_src = (int*)(Wt16 + 2 * D * D);           // E
    float*         wpart   = (float*)(csr_src + N_EDGES);        // WG*N floats (25.6 MB)
    unsigned int*  cpart   = (unsigned int*)(wpart + (size_t)WG * N_NODES); // WG*N/4 (6.4 MB)
    unsigned int*  pp      = cpart + (size_t)WG * (N_NODES / 4); // CHK*PP_STRIDE (12.8 MB)
    unsigned char* x8      = (unsigned char*)pp;                 // N*D fp8 (12.8 MB, aliases pp)
    __half*        agg16   = (__half*)(pp + (size_t)CHK * PP_STRIDE); // N*D fp16 (25.6 MB)

    // ---- CSR build (dst only) + nd ----
    k_hist<<<HR * CHK, 256, 0, stream>>>(dst, pp);
    k_merge<<<(PP_STRIDE + 255) / 256, 256, 0, stream>>>(pp, cnt_dst);
    k_scan1<<<SCAN_NB, 1024, 0, stream>>>(cnt_dst, rpD + 1, bsD);
    k_scan2<<<1, 128, 0, stream>>>(bsD);
    k_scan3nd<<<(N_NODES + 255) / 256, 256, 0, stream>>>(rpD, bsD, cnt_dst, nd, colsum);
    k_scatter_dst<<<NSH4 * CHK, 256, 0, stream>>>(src, dst, rpD, pp, csr_src);
    // ---- ns + wsum in one streaming pass (absorbs src histogram) ----
    k_wacc<<<WR * WG, 256, 0, stream>>>(src, dst, nd, wpart, cpart);
    k_wmerge<<<(N_NODES + 255) / 256, 256, 0, stream>>>(wpart, cpart, ns, wsum);

    // Wt + x0 = fp8(h*ns)  (x8 overwrites pp region — stream-ordered after scatter)
    k_prep<<<128 + (N_NODES * (D / 4) + 255) / 256, 256, 0, stream>>>(
        W0, W1, Wt16, h, ns, (unsigned int*)x8);

    // layer 0
    k_spmm<<<(N_NODES + 3) / 4, 256, 0, stream>>>(x8, rpD, csr_src, agg16);
    k_gemm_mfma<<<(N_NODES + 127) / 128, 256, 0, stream>>>(agg16, Wt16, b0, nd, ns, x8);
    // layer 1 + fused layer-2 reduction
    k_spmm<<<(N_NODES + 3) / 4, 256, 0, stream>>>(x8, rpD, csr_src, agg16);
    k_gemm_red<<<(N_NODES + 127) / 128, 256, 0, stream>>>(agg16, Wt16 + (size_t)D * D,
                                                          b1, nd, wsum, colsum);
    k_final<<<1, 128, 0, stream>>>(colsum, W2, b2, out);
}

// Round 16
// 434.925 us; speedup vs baseline: 1.1762x; 1.1762x over previous
//
#include <hip/hip_runtime.h>
#include <hip/hip_fp16.h>

#define N_NODES 100000
#define N_EDGES 1600000
#define D 128
#define SCAN_NB ((N_NODES + 1023) / 1024)   // 98
#define CHK 128                             // edge chunks
#define CHUNK_E (N_EDGES / CHK)             // 12500 edges/chunk
#define QTR_N 25000                         // hist: nodes per quarter
#define QTR_U (QTR_N / 4)                   // 6250 uints (8-bit packed, 25 KB LDS)
#define PP_STRIDE (N_NODES / 4)             // 25000 uints per (arr,chunk)
#define NSH4 4                              // scatter shards (R8-proven config)
#define SH4 (N_NODES / NSH4)                // 25000 nodes/shard
#define SH4_U (SH4 / 4)                     // 6250 uints (25 KB LDS)

typedef _Float16 f16x4 __attribute__((ext_vector_type(4)));
typedef _Float16 f16x8 __attribute__((ext_vector_type(8)));
typedef float f32x4 __attribute__((ext_vector_type(4)));
typedef float f32x2 __attribute__((ext_vector_type(2)));

// ---------------------------------------------------------------------------
// Pass A: LDS histograms, 8-bit packed (4 nodes/uint), quarter node-ranges.
// block = (arr, quarter, chunk); 1024 blocks; 25 KB LDS (~5 blk/CU).
__global__ __launch_bounds__(256) void
k_hist(const int* __restrict__ src, const int* __restrict__ dst,
       unsigned int* __restrict__ pp) {
    __shared__ unsigned int h[QTR_U];  // 25 KB
    int b = blockIdx.x;
    int arr = b >> 9, q = (b >> 7) & 3, c = b & (CHK - 1);
    const int* a = arr ? dst : src;
    int lo = q * QTR_N;
    for (int i = threadIdx.x; i < QTR_U; i += 256) h[i] = 0;
    __syncthreads();
    int e0 = c * CHUNK_E;
    for (int i = e0 + threadIdx.x; i < e0 + CHUNK_E; i += 256) {
        int v = a[i] - lo;
        if ((unsigned)v < QTR_N)
            atomicAdd(&h[v >> 2], 1u << ((v & 3) * 8));
    }
    __syncthreads();
    unsigned int* po = pp + ((size_t)(arr * CHK + c)) * PP_STRIDE + q * QTR_U;
    for (int i = threadIdx.x; i < QTR_U; i += 256) po[i] = h[i];
}

// Pass B: totals -> cnt; partials -> exclusive per-chunk prefix (8-bit),
// in place, BOTH arrays (src prefix feeds scatter_src, dst feeds scatter_dst).
__global__ void k_merge(unsigned int* __restrict__ pp,
                        int* __restrict__ cnt_src, int* __restrict__ cnt_dst) {
    int g = blockIdx.x * blockDim.x + threadIdx.x;
    if (g >= 2 * PP_STRIDE) return;
    int arr = g / PP_STRIDE, u = g % PP_STRIDE;
    unsigned int* p = pp + ((size_t)arr * CHK) * PP_STRIDE + u;
    int s0 = 0, s1 = 0, s2 = 0, s3 = 0;
#pragma unroll 8
    for (int c = 0; c < CHK; c++) {
        unsigned int v = p[(size_t)c * PP_STRIDE];
        p[(size_t)c * PP_STRIDE] =
            (unsigned)s0 | ((unsigned)s1 << 8) | ((unsigned)s2 << 16) | ((unsigned)s3 << 24);
        s0 += v & 255; s1 += (v >> 8) & 255; s2 += (v >> 16) & 255; s3 += (v >> 24) & 255;
    }
    int* cnt = arr ? cnt_dst : cnt_src;
    cnt[4 * u + 0] = s0; cnt[4 * u + 1] = s1; cnt[4 * u + 2] = s2; cnt[4 * u + 3] = s3;
}

// scan both cnt arrays: blocks [0,98) -> dst/rpD, [98,196) -> src/rpS
__global__ __launch_bounds__(1024) void
k_scan1(const int* __restrict__ cnt_dst, const int* __restrict__ cnt_src,
        int* __restrict__ rpD, int* __restrict__ rpS,
        int* __restrict__ bsD, int* __restrict__ bsS) {
    __shared__ int s[1024];
    int arr = blockIdx.x / SCAN_NB, bb = blockIdx.x % SCAN_NB;
    const int* cnt = arr ? cnt_src : cnt_dst;
    int* rp1 = (arr ? rpS : rpD) + 1;
    int* bs = arr ? bsS : bsD;
    int tid = threadIdx.x;
    int i = bb * 1024 + tid;
    int v = (i < N_NODES) ? cnt[i] : 0;
    s[tid] = v;
    __syncthreads();
    for (int d = 1; d < 1024; d <<= 1) {
        int t = (tid >= d) ? s[tid - d] : 0;
        __syncthreads();
        s[tid] += t;
        __syncthreads();
    }
    if (i < N_NODES) rp1[i] = s[tid];
    if (tid == 1023) bs[bb] = s[1023];
}

__global__ void k_scan2(int* __restrict__ bsD, int* __restrict__ bsS) {
    __shared__ int s[128];
    int* bs = blockIdx.x ? bsS : bsD;
    int tid = threadIdx.x;
    int v = (tid < SCAN_NB) ? bs[tid] : 0;
    s[tid] = v;
    __syncthreads();
    for (int d = 1; d < 128; d <<= 1) {
        int t = (tid >= d) ? s[tid - d] : 0;
        __syncthreads();
        s[tid] += t;
        __syncthreads();
    }
    if (tid < SCAN_NB) bs[tid] = s[tid] - v;  // exclusive
}

// finalize both row_ptrs + norms + zero colsum
__global__ void k_scan3norm(int* __restrict__ rpD, int* __restrict__ rpS,
                            const int* __restrict__ bsD, const int* __restrict__ bsS,
                            const int* __restrict__ cnt_src, const int* __restrict__ cnt_dst,
                            float* __restrict__ ns, float* __restrict__ nd,
                            float* __restrict__ colsum) {
    int i = blockIdx.x * blockDim.x + threadIdx.x;
    if (i >= N_NODES) return;
    rpD[1 + i] += bsD[i >> 10];
    rpS[1 + i] += bsS[i >> 10];
    if (i == 0) { rpD[0] = 0; rpS[0] = 0; }
    if (i < 128) colsum[i] = 0.0f;
    ns[i] = rsqrtf((float)max(cnt_src[i], 1));
    nd[i] = rsqrtf((float)max(cnt_dst[i], 1));
}

// Pass C1: counting-sort by dst, payload src. Separate kernel, 4 shards,
// 512 blocks, 25 KB LDS 8-bit rank counters (R8-proven; merged variants
// measured 10x payload WRITE from cross-XCD line ping-pong).
__global__ __launch_bounds__(256) void
k_scatter_dst(const int* __restrict__ src, const int* __restrict__ dst,
              const int* __restrict__ rpD, const unsigned int* __restrict__ pp,
              int* __restrict__ csr_src) {
    __shared__ unsigned int cur[SH4_U];  // 25 KB
    int sh = blockIdx.x & 3, c = blockIdx.x >> 2;
    int lo = sh * SH4;
    const unsigned int* pre = pp + ((size_t)(CHK + c)) * PP_STRIDE;  // arr=1 (dst)
    for (int i = threadIdx.x; i < SH4_U; i += 256) cur[i] = 0;
    __syncthreads();
    int e0 = c * CHUNK_E;
    for (int i = e0 + threadIdx.x; i < e0 + CHUNK_E; i += 256) {
        int dfull = dst[i];
        int d = dfull - lo;
        if ((unsigned)d < SH4) {
            int sft = (d & 3) * 8;
            int rank = (atomicAdd(&cur[d >> 2], 1u << sft) >> sft) & 255;
            int p8 = (pre[dfull >> 2] >> ((dfull & 3) * 8)) & 255;
            csr_src[rpD[dfull] + p8 + rank] = src[i];
        }
    }
}

// Pass C2: counting-sort by src, payload nd[dst] -> csrv.
__global__ __launch_bounds__(256) void
k_scatter_src(const int* __restrict__ src, const int* __restrict__ dst,
              const int* __restrict__ rpS, const unsigned int* __restrict__ pp,
              const float* __restrict__ nd, float* __restrict__ csrv) {
    __shared__ unsigned int cur[SH4_U];  // 25 KB
    int sh = blockIdx.x & 3, c = blockIdx.x >> 2;
    int lo = sh * SH4;
    const unsigned int* pre = pp + (size_t)c * PP_STRIDE;  // arr=0 (src)
    for (int i = threadIdx.x; i < SH4_U; i += 256) cur[i] = 0;
    __syncthreads();
    int e0 = c * CHUNK_E;
    for (int i = e0 + threadIdx.x; i < e0 + CHUNK_E; i += 256) {
        int sfull = src[i];
        int s = sfull - lo;
        if ((unsigned)s < SH4) {
            int sft = (s & 3) * 8;
            int rank = (atomicAdd(&cur[s >> 2], 1u << sft) >> sft) & 255;
            int p8 = (pre[sfull >> 2] >> ((sfull & 3) * 8)) & 255;
            csrv[rpS[sfull] + p8 + rank] = nd[dst[i]];
        }
    }
}

// wsum[n] = ns[n] * sum of csrv over n's src-list (coalesced segment sums)
__global__ void k_wsum(const int* __restrict__ rpS, const float* __restrict__ csrv,
                       const float* __restrict__ ns, float* __restrict__ wsum) {
    int gid = blockIdx.x * blockDim.x + threadIdx.x;
    int wv = gid >> 6, lane = gid & 63;
    int n = wv * 16 + (lane & 15);
    int off = lane >> 4;
    float s = 0.0f;
    int beg = 0, end = 0;
    if (n < N_NODES) { beg = rpS[n]; end = rpS[n + 1]; }
    for (int j = beg + off; j < end; j += 4) s += csrv[j];
    s += __shfl_xor(s, 16, 64);
    s += __shfl_xor(s, 32, 64);
    if (n < N_NODES && lane < 16) wsum[n] = s * ns[n];
}

// fused prep: blocks [0,128): Wt16[l][n][k] = half(Wl[k][n]);
//             blocks [128,...): x8[n][:] = fp8(h[n][:] * ns[n])
__global__ void k_prep(const float* __restrict__ W0, const float* __restrict__ W1,
                       __half* __restrict__ Wt, const float* __restrict__ x,
                       const float* __restrict__ ns, unsigned int* __restrict__ out) {
    if (blockIdx.x < 128) {
        int i = blockIdx.x * 256 + threadIdx.x;  // over 2*D*D
        int l = i >> 14, r = i & (D * D - 1);
        int n = r >> 7, k = r & 127;
        const float* W = l ? W1 : W0;
        Wt[i] = __float2half(W[k * D + n]);
        return;
    }
    int i = (blockIdx.x - 128) * 256 + threadIdx.x;  // over N*D/4
    if (i >= N_NODES * (D / 4)) return;
    int n = i >> 5;
    float4 v = ((const float4*)x)[i];
    float s = ns[n];
    int u = __builtin_amdgcn_cvt_pk_fp8_f32(v.x * s, v.y * s, 0, false);
    u = __builtin_amdgcn_cvt_pk_fp8_f32(v.z * s, v.w * s, u, true);
    out[i] = (unsigned int)u;
}

// pull SpMM (fp8 gather -> fp32 accum -> fp16 agg): one wave per node,
// 2 edges per gather instruction (lane reads uint = 4 fp8; 32 lanes/row).
__global__ __launch_bounds__(256) void
k_spmm(const unsigned char* __restrict__ x8, const int* __restrict__ row_ptr,
       const int* __restrict__ csr_src, __half* __restrict__ agg) {
    int wave = (blockIdx.x * blockDim.x + threadIdx.x) >> 6;
    int lane = threadIdx.x & 63;
    int hf = lane >> 5, l32 = lane & 31;
    if (wave >= N_NODES) return;
    int beg = row_ptr[wave], end = row_ptr[wave + 1];
    float a0 = 0.f, a1 = 0.f, a2 = 0.f, a3 = 0.f;
    int j = beg;
    for (; j + 7 < end; j += 8) {
#pragma unroll
        for (int p = 0; p < 4; p++) {
            int s0 = csr_src[j + 2 * p];
            int s1 = csr_src[j + 2 * p + 1];
            int s = hf ? s1 : s0;
            unsigned int u = *(const unsigned int*)(x8 + (size_t)s * D + 4 * l32);
            f32x2 lo = __builtin_amdgcn_cvt_pk_f32_fp8(u, false);
            f32x2 hi = __builtin_amdgcn_cvt_pk_f32_fp8(u, true);
            a0 += lo[0]; a1 += lo[1]; a2 += hi[0]; a3 += hi[1];
        }
    }
    for (; j + 1 < end; j += 2) {
        int s0 = csr_src[j], s1 = csr_src[j + 1];
        int s = hf ? s1 : s0;
        unsigned int u = *(const unsigned int*)(x8 + (size_t)s * D + 4 * l32);
        f32x2 lo = __builtin_amdgcn_cvt_pk_f32_fp8(u, false);
        f32x2 hi = __builtin_amdgcn_cvt_pk_f32_fp8(u, true);
        a0 += lo[0]; a1 += lo[1]; a2 += hi[0]; a3 += hi[1];
    }
    if (j < end && hf == 0) {
        int s = csr_src[j];
        unsigned int u = *(const unsigned int*)(x8 + (size_t)s * D + 4 * l32);
        f32x2 lo = __builtin_amdgcn_cvt_pk_f32_fp8(u, false);
        f32x2 hi = __builtin_amdgcn_cvt_pk_f32_fp8(u, true);
        a0 += lo[0]; a1 += lo[1]; a2 += hi[0]; a3 += hi[1];
    }
    a0 += __shfl_xor(a0, 32, 64);
    a1 += __shfl_xor(a1, 32, 64);
    a2 += __shfl_xor(a2, 32, 64);
    a3 += __shfl_xor(a3, 32, 64);
    if (hf == 0) {
        f16x4 o;
        o[0] = (_Float16)a0; o[1] = (_Float16)a1; o[2] = (_Float16)a2; o[3] = (_Float16)a3;
        ((f16x4*)(agg + (size_t)wave * D))[l32] = o;
    }
}

// MFMA GEMM (layer 0): A fp16 (agg), out fp8 rows (pre-scaled by ns).
__global__ __launch_bounds__(256) void
k_gemm_mfma(const __half* __restrict__ A, const __half* __restrict__ Wt,
            const float* __restrict__ b, const float* __restrict__ nd,
            const float* __restrict__ ns, unsigned char* __restrict__ out) {
    int w = threadIdx.x >> 6, lane = threadIdx.x & 63;
    int m = lane & 15, q = lane >> 4;
    int row0 = blockIdx.x * 128 + w * 32;

    f16x8 zf;
#pragma unroll
    for (int j = 0; j < 8; j++) zf[j] = (_Float16)0;
    f16x8 af[2][4];
#pragma unroll
    for (int g = 0; g < 2; g++) {
        int arow = row0 + g * 16 + m;
        const f16x8* pa = (const f16x8*)(A + (size_t)arow * D);
        bool aok = arow < N_NODES;
#pragma unroll
        for (int ks = 0; ks < 4; ks++) af[g][ks] = aok ? pa[ks * 4 + q] : zf;
    }

    const f16x8* pb = (const f16x8*)Wt;
    f32x4 acc[2][8];
#pragma unroll
    for (int g = 0; g < 2; g++)
#pragma unroll
        for (int nt = 0; nt < 8; nt++) acc[g][nt] = (f32x4){0.f, 0.f, 0.f, 0.f};

#pragma unroll
    for (int ks = 0; ks < 4; ks++) {
#pragma unroll
        for (int nt = 0; nt < 8; nt++) {
            f16x8 bf = pb[((nt * 16 + m) << 4) + (ks << 2) + q];
            acc[0][nt] = __builtin_amdgcn_mfma_f32_16x16x32_f16(af[0][ks], bf, acc[0][nt], 0, 0, 0);
            acc[1][nt] = __builtin_amdgcn_mfma_f32_16x16x32_f16(af[1][ks], bf, acc[1][nt], 0, 0, 0);
        }
    }

#pragma unroll
    for (int g = 0; g < 2; g++) {
        int er = row0 + g * 16 + q * 4;
        float sd[4], ss[4];
#pragma unroll
        for (int r = 0; r < 4; r++) {
            int n = er + r;
            bool ok = n < N_NODES;
            sd[r] = ok ? nd[n] : 0.0f;
            ss[r] = ok ? ns[n] : 0.0f;
        }
#pragma unroll
        for (int nt = 0; nt < 8; nt++) {
            int col = nt * 16 + m;
            float bc = b[col];
#pragma unroll
            for (int r = 0; r < 4; r++) {
                int n = er + r;
                if (n < N_NODES) {
                    float v = fmaxf(sd[r] * acc[g][nt][r] + bc, 0.0f) * ss[r];
                    int pk = __builtin_amdgcn_cvt_pk_fp8_f32(v, v, 0, false);
                    out[(size_t)n * D + col] = (unsigned char)(pk & 0xff);
                }
            }
        }
    }
}

// MFMA GEMM (layer 1 + fused final reduction):
// colsum[col] += sum_n wsum[n] * relu(nd[n]*(A@W1)[n][col] + b1[col])
__global__ __launch_bounds__(256) void
k_gemm_red(const __half* __restrict__ A, const __half* __restrict__ Wt,
           const float* __restrict__ b, const float* __restrict__ nd,
           const float* __restrict__ wsum, float* __restrict__ colsum) {
    __shared__ float red[128];
    int tid = threadIdx.x;
    if (tid < 128) red[tid] = 0.0f;
    __syncthreads();

    int w = tid >> 6, lane = tid & 63;
    int m = lane & 15, q = lane >> 4;
    int row0 = blockIdx.x * 128 + w * 32;

    f16x8 zf;
#pragma unroll
    for (int j = 0; j < 8; j++) zf[j] = (_Float16)0;
    f16x8 af[2][4];
#pragma unroll
    for (int g = 0; g < 2; g++) {
        int arow = row0 + g * 16 + m;
        const f16x8* pa = (const f16x8*)(A + (size_t)arow * D);
        bool aok = arow < N_NODES;
#pragma unroll
        for (int ks = 0; ks < 4; ks++) af[g][ks] = aok ? pa[ks * 4 + q] : zf;
    }

    const f16x8* pb = (const f16x8*)Wt;
    f32x4 acc[2][8];
#pragma unroll
    for (int g = 0; g < 2; g++)
#pragma unroll
        for (int nt = 0; nt < 8; nt++) acc[g][nt] = (f32x4){0.f, 0.f, 0.f, 0.f};

#pragma unroll
    for (int ks = 0; ks < 4; ks++) {
#pragma unroll
        for (int nt = 0; nt < 8; nt++) {
            f16x8 bf = pb[((nt * 16 + m) << 4) + (ks << 2) + q];
            acc[0][nt] = __builtin_amdgcn_mfma_f32_16x16x32_f16(af[0][ks], bf, acc[0][nt], 0, 0, 0);
            acc[1][nt] = __builtin_amdgcn_mfma_f32_16x16x32_f16(af[1][ks], bf, acc[1][nt], 0, 0, 0);
        }
    }

    float sd[2][4], sw[2][4];
#pragma unroll
    for (int g = 0; g < 2; g++) {
        int er = row0 + g * 16 + q * 4;
#pragma unroll
        for (int r = 0; r < 4; r++) {
            int n = er + r;
            bool ok = n < N_NODES;
            sd[g][r] = ok ? nd[n] : 0.0f;
            sw[g][r] = ok ? wsum[n] : 0.0f;
        }
    }
#pragma unroll
    for (int nt = 0; nt < 8; nt++) {
        int col = nt * 16 + m;
        float bc = b[col];
        float pc = 0.0f;
#pragma unroll
        for (int g = 0; g < 2; g++)
#pragma unroll
            for (int r = 0; r < 4; r++)
                pc += sw[g][r] * fmaxf(sd[g][r] * acc[g][nt][r] + bc, 0.0f);
        atomicAdd(&red[col], pc);
    }
    __syncthreads();
    if (tid < 128) unsafeAtomicAdd(&colsum[tid], red[tid]);
}

// out[j] = (colsum/N) @ W2 [:,j] + b2[j]
__global__ void k_final(const float* __restrict__ colsum, const float* __restrict__ W,
                        const float* __restrict__ b, float* __restrict__ out) {
    __shared__ float m[128];
    int j = threadIdx.x;
    m[j] = colsum[j] * (1.0f / N_NODES);
    __syncthreads();
    float acc = b[j];
    for (int k = 0; k < 128; k++)
        acc = fmaf(m[k], W[(size_t)k * D + j], acc);
    out[j] = acc;
}

extern "C" void kernel_launch(void* const* d_in, const int* in_sizes, int n_in,
                              void* d_out, int out_size, void* d_ws, size_t ws_size,
                              hipStream_t stream) {
    const float* h   = (const float*)d_in[0];
    const int*   src = (const int*)d_in[1];
    const int*   dst = (const int*)d_in[2];
    const float* W0  = (const float*)d_in[3];
    const float* b0  = (const float*)d_in[4];
    const float* W1  = (const float*)d_in[5];
    const float* b1  = (const float*)d_in[6];
    const float* W2  = (const float*)d_in[7];
    const float* b2  = (const float*)d_in[8];
    float* out = (float*)d_out;

    // workspace (~67 MB); pp (25.6 MB) dead after scatters -> x8 aliases it
    float*         ns      = (float*)d_ws;                       // N
    float*         nd      = ns + N_NODES;                       // N
    float*         wsum    = nd + N_NODES;                       // N
    float*         colsum  = wsum + N_NODES;                     // 128
    int*           rpD     = (int*)(colsum + 128);               // N+1
    int*           rpS     = rpD + N_NODES + 1;                  // N+1
    int*           cnt_src = rpS + N_NODES + 1;                  // N
    int*           cnt_dst = cnt_src + N_NODES;                  // N
    int*           bsD     = cnt_dst + N_NODES;                  // 128
    int*           bsS     = bsD + 128;                          // 128
    __half*        Wt16    = (__half*)(bsS + 128);               // 2*D*D
    int*           csr_src = (int*)(Wt16 + 2 * D * D);           // E
    float*         csrv    = (float*)(csr_src + N_EDGES);        // E
    unsigned int*  pp      = (unsigned int*)(csrv + N_EDGES);    // 25.6 MB
    unsigned char* x8      = (unsigned char*)pp;                 // N*D fp8 (12.8 MB, aliases pp)
    __half*        agg16   = (__half*)(pp + 2 * (size_t)CHK * PP_STRIDE); // N*D fp16

    // ---- CSR build (both directions) + norms + wsum; no global atomics ----
    k_hist<<<2 * 4 * CHK, 256, 0, stream>>>(src, dst, pp);
    k_merge<<<(2 * PP_STRIDE + 255) / 256, 256, 0, stream>>>(pp, cnt_src, cnt_dst);
    k_scan1<<<2 * SCAN_NB, 1024, 0, stream>>>(cnt_dst, cnt_src, rpD, rpS, bsD, bsS);
    k_scan2<<<2, 128, 0, stream>>>(bsD, bsS);
    k_scan3norm<<<(N_NODES + 255) / 256, 256, 0, stream>>>(rpD, rpS, bsD, bsS,
                                                           cnt_src, cnt_dst, ns, nd, colsum);
    k_scatter_dst<<<NSH4 * CHK, 256, 0, stream>>>(src, dst, rpD, pp, csr_src);
    k_scatter_src<<<NSH4 * CHK, 256, 0, stream>>>(src, dst, rpS, pp, nd, csrv);
    k_wsum<<<(N_NODES * 4 + 255) / 256, 256, 0, stream>>>(rpS, csrv, ns, wsum);

    // Wt + x0 = fp8(h*ns)  (x8 overwrites pp region — stream-ordered after scatters)
    k_prep<<<128 + (N_NODES * (D / 4) + 255) / 256, 256, 0, stream>>>(
        W0, W1, Wt16, h, ns, (unsigned int*)x8);

    // layer 0
    k_spmm<<<(N_NODES + 3) / 4, 256, 0, stream>>>(x8, rpD, csr_src, agg16);
    k_gemm_mfma<<<(N_NODES + 127) / 128, 256, 0, stream>>>(agg16, Wt16, b0, nd, ns, x8);
    // layer 1 + fused layer-2 reduction
    k_spmm<<<(N_NODES + 3) / 4, 256, 0, stream>>>(x8, rpD, csr_src, agg16);
    k_gemm_red<<<(N_NODES + 127) / 128, 256, 0, stream>>>(agg16, Wt16 + (size_t)D * D,
                                                          b1, nd, wsum, colsum);
    k_final<<<1, 128, 0, stream>>>(colsum, W2, b2, out);
}